// Round 1
// baseline (4046.214 us; speedup 1.0000x reference)
//
#include <hip/hip_runtime.h>
#include <math.h>

#define NS 100000
#define NB 50000
#define EE 1600000
#define DH 32

__host__ __device__ constexpr int nd_of(int r) { return (r == 2 || r == 3) ? NB : NS; }
__host__ __device__ constexpr int rs_off(int r) { int o = 0; for (int i = 0; i < r; i++) o += nd_of(i) + 1; return o; }
__host__ __device__ constexpr int cur_off(int r) { int o = 0; for (int i = 0; i < r; i++) o += nd_of(i); return o; }

struct Rel {
    const float* xsrc;   // [n_src, D_IN]
    const int* rs;       // row_start, n_dst+1
    const int* srcs;     // CSR-ordered src indices, [E]
    const float* W;      // [D_IN*32]
    const float* b;      // [32]
    const float* Wroot;  // [D_IN*32]
};

// ---------------- CSR build ----------------

__global__ __launch_bounds__(256) void count_kernel(
    const int* __restrict__ e0, const int* __restrict__ e1, const int* __restrict__ e2,
    const int* __restrict__ e3, const int* __restrict__ e4, int* __restrict__ cur)
{
    int i = blockIdx.x * 256 + threadIdx.x;
    if (i >= 5 * EE) return;
    int r = i / EE, e = i - r * EE;
    const int* ei = (r == 0) ? e0 : (r == 1) ? e1 : (r == 2) ? e2 : (r == 3) ? e3 : e4;
    atomicAdd(&cur[cur_off(r) + ei[EE + e]], 1);
}

__global__ __launch_bounds__(1024) void scan_kernel(int* __restrict__ cur, int* __restrict__ rs)
{
    int r = blockIdx.x;
    int n = nd_of(r);
    int* deg = cur + cur_off(r);
    int* rso = rs + rs_off(r);
    __shared__ int s[1024];
    int tid = threadIdx.x;
    int carry = 0;
    for (int b = 0; b < n; b += 1024) {
        int i = b + tid;
        int v = (i < n) ? deg[i] : 0;
        s[tid] = v;
        __syncthreads();
        for (int off = 1; off < 1024; off <<= 1) {
            int t = (tid >= off) ? s[tid - off] : 0;
            __syncthreads();
            s[tid] += t;
            __syncthreads();
        }
        if (i < n) { int ex = carry + s[tid] - v; rso[i] = ex; deg[i] = ex; }  // cursor := row_start
        carry += s[1023];
        __syncthreads();
    }
    if (tid == 0) rso[n] = carry;
}

__global__ __launch_bounds__(256) void scatter_kernel(
    const int* __restrict__ e0, const int* __restrict__ e1, const int* __restrict__ e2,
    const int* __restrict__ e3, const int* __restrict__ e4,
    int* __restrict__ cur, int* __restrict__ srcs)
{
    int i = blockIdx.x * 256 + threadIdx.x;
    if (i >= 5 * EE) return;
    int r = i / EE, e = i - r * EE;
    const int* ei = (r == 0) ? e0 : (r == 1) ? e1 : (r == 2) ? e2 : (r == 3) ? e3 : e4;
    int pos = atomicAdd(&cur[cur_off(r) + ei[EE + e]], 1);
    srcs[r * EE + pos] = ei[e];
}

// ---------------- fused layer ----------------
// AGGR: 0=add, 1=mean, 2=max

template <int D_IN, int AGGR>
__device__ __forceinline__ void do_rel(const Rel& R, int node, int lane, int tid,
                                       float* sW, float& out_acc)
{
    __syncthreads();  // protect previous sW readers
    for (int i = tid; i < D_IN * 32; i += 256) sW[i] = R.W[i];
    __syncthreads();

    int s0 = R.rs[node], s1 = R.rs[node + 1];
    float acc = (AGGR == 2) ? -INFINITY : 0.f;
    #pragma unroll 4
    for (int e = s0; e < s1; ++e) {
        int src = R.srcs[e];
        float v = (lane < D_IN) ? R.xsrc[src * D_IN + lane] : 0.f;
        if (AGGR == 2) acc = fmaxf(acc, v); else acc += v;
    }
    int deg = s1 - s0;
    if (AGGR == 1) acc *= 1.f / (float)max(deg, 1);
    if (AGGR == 2 && deg == 0) acc = 0.f;

    #pragma unroll
    for (int k = 0; k < D_IN; ++k) {
        float a = __shfl(acc, k, 32);
        out_acc = fmaf(a, sW[k * 32 + lane], out_acc);
    }
}

template <int D_IN, int NREL, bool RES, bool RELU, int A0, int A1, int A2>
__global__ __launch_bounds__(256) void layer_kernel(
    Rel r0, Rel r1, Rel r2,
    const float* __restrict__ x_dst, float* __restrict__ out)
{
    __shared__ float sW[32 * 32];
    int tid = threadIdx.x;
    int lane = tid & 31, nl = tid >> 5;
    int node = blockIdx.x * 8 + nl;   // grid sized exactly: n_dst % 8 == 0

    // summed root weights into LDS
    for (int i = tid; i < D_IN * 32; i += 256) {
        float w = r0.Wroot[i];
        if (NREL > 1) w += r1.Wroot[i];
        if (NREL > 2) w += r2.Wroot[i];
        sW[i] = w;
    }
    float out_acc = r0.b[lane];
    if (NREL > 1) out_acc += r1.b[lane];
    if (NREL > 2) out_acc += r2.b[lane];
    __syncthreads();

    float xrow = (lane < D_IN) ? x_dst[node * D_IN + lane] : 0.f;
    #pragma unroll
    for (int k = 0; k < D_IN; ++k)
        out_acc = fmaf(__shfl(xrow, k, 32), sW[k * 32 + lane], out_acc);
    if (RES) out_acc += xrow;  // residual (D_IN==32 when RES)

    do_rel<D_IN, A0>(r0, node, lane, tid, sW, out_acc);
    if (NREL > 1) do_rel<D_IN, A1>(r1, node, lane, tid, sW, out_acc);
    if (NREL > 2) do_rel<D_IN, A2>(r2, node, lane, tid, sW, out_acc);

    if (RELU) out_acc = fmaxf(out_acc, 0.f);
    out[node * 32 + lane] = out_acc;
}

// ---------------- host ----------------

extern "C" void kernel_launch(void* const* d_in, const int* in_sizes, int n_in,
                              void* d_out, int out_size, void* d_ws, size_t ws_size,
                              hipStream_t stream)
{
    const float* x_stroke = (const float*)d_in[0];
    const float* x_brep   = (const float*)d_in[1];
    const int* ei0 = (const int*)d_in[2];
    const int* ei1 = (const int*)d_in[3];
    const int* ei2 = (const int*)d_in[4];
    const int* ei3 = (const int*)d_in[5];
    const int* ei4 = (const int*)d_in[6];
    const float* W0_rel  = (const float*)d_in[7];
    const float* b0_rel  = (const float*)d_in[8];
    const float* W0_root = (const float*)d_in[9];
    const float* Wb_rel  = (const float*)d_in[10];
    const float* bb_rel  = (const float*)d_in[11];
    const float* Wb_root = (const float*)d_in[12];
    float* out = (float*)d_out;

    // workspace layout (elements of 4 bytes)
    int* srcs = (int*)d_ws;                       // 5*EE
    int* rs   = srcs + 5 * EE;                    // rs_off(5) = 400005
    int* cur  = rs + rs_off(5);                   // cur_off(5) = 400000
    float* xs0 = (float*)(cur + cur_off(5));      // NS*32
    float* xs1 = xs0 + NS * 32;
    float* xb0 = xs1 + NS * 32;                   // NB*32
    float* xb1 = xb0 + NB * 32;

    // ---- CSR build (once per call) ----
    hipMemsetAsync(cur, 0, cur_off(5) * sizeof(int), stream);
    int gE = (5 * EE + 255) / 256;
    count_kernel<<<gE, 256, 0, stream>>>(ei0, ei1, ei2, ei3, ei4, cur);
    scan_kernel<<<5, 1024, 0, stream>>>(cur, rs);
    scatter_kernel<<<gE, 256, 0, stream>>>(ei0, ei1, ei2, ei3, ei4, cur, srcs);

    // weight pointer helpers
    auto relW = [&](int l, int r) -> const float* {
        return l == 0 ? W0_rel + r * 6 * 32 : Wb_rel + ((l - 1) * 5 + r) * 32 * 32;
    };
    auto relB = [&](int l, int r) -> const float* {
        return l == 0 ? b0_rel + r * 32 : bb_rel + ((l - 1) * 5 + r) * 32;
    };
    auto relWr = [&](int l, int r) -> const float* {
        return l == 0 ? W0_root + r * 6 * 32 : Wb_root + ((l - 1) * 5 + r) * 32 * 32;
    };
    auto mkrel = [&](int l, int r, const float* xsrc) -> Rel {
        Rel R;
        R.xsrc = xsrc; R.rs = rs + rs_off(r); R.srcs = srcs + r * EE;
        R.W = relW(l, r); R.b = relB(l, r); R.Wroot = relWr(l, r);
        return R;
    };

    const int GS = NS / 8, GB = NB / 8;

    // layer 0 (inputs d=6, no residual)
    {
        Rel s0 = mkrel(0, 0, x_stroke), s1 = mkrel(0, 1, x_stroke), s2 = mkrel(0, 4, x_stroke);
        layer_kernel<6, 3, false, false, 1, 0, 2><<<GS, 256, 0, stream>>>(s0, s1, s2, x_stroke, xs0);
        Rel b0 = mkrel(0, 2, x_stroke), b1 = mkrel(0, 3, x_brep);
        layer_kernel<6, 2, false, false, 1, 2, 0><<<GB, 256, 0, stream>>>(b0, b1, b1, x_brep, xb0);
    }

    // layers 1..4 (d=32, residual; layer 4 writes relu'd d_out)
    const float* cs = xs0; const float* cb = xb0;
    float* outs_s[4] = { xs1, xs0, xs1, out };
    float* outs_b[4] = { xb1, xb0, xb1, out + NS * 32 };
    for (int l = 1; l <= 4; ++l) {
        float* os = outs_s[l - 1];
        float* ob = outs_b[l - 1];
        Rel s0 = mkrel(l, 0, cs), s1 = mkrel(l, 1, cs), s2 = mkrel(l, 4, cs);
        Rel b0 = mkrel(l, 2, cs), b1 = mkrel(l, 3, cb);
        if (l < 4) {
            layer_kernel<32, 3, true, false, 1, 0, 2><<<GS, 256, 0, stream>>>(s0, s1, s2, cs, os);
            layer_kernel<32, 2, true, false, 1, 2, 0><<<GB, 256, 0, stream>>>(b0, b1, b1, cb, ob);
        } else {
            layer_kernel<32, 3, true, true, 1, 0, 2><<<GS, 256, 0, stream>>>(s0, s1, s2, cs, os);
            layer_kernel<32, 2, true, true, 1, 2, 0><<<GB, 256, 0, stream>>>(b0, b1, b1, cb, ob);
        }
        cs = os; cb = ob;
    }
    (void)in_sizes; (void)n_in; (void)out_size; (void)ws_size;
}